// Round 17
// baseline (264.206 us; speedup 1.0000x reference)
//
#include <hip/hip_runtime.h>
#include <math.h>

#define NTOT   65536
#define DDIM   256
#define BATCH  2048
#define NPREV  (NTOT - BATCH)   // 63488

#define PWP    32               // partial width, prev (32 chunks)
#define PWR    32               // partial width, reached
#define UPC_P  31               // units (64-col x 256-k) per chunk, prev
#define UPC_R  1                // reached
#define BNC_P  31               // fallback chunking
#define BNC_R  16

#define INF_F 3.402823466e+38f
#define SWZ(r) ((((r) & 3)) ^ ((((r) >> 2) & 3)))

typedef float  f32x4  __attribute__((ext_vector_type(4)));
typedef float  f32x16 __attribute__((ext_vector_type(16)));
typedef _Float16 half8 __attribute__((ext_vector_type(8)));

#define TILE_HALVES 65536   // per 128-row tile image (128r x 256k x hi/lo)

// ---------------- row norms (fallback path) ----------------
__global__ void lp_norms(const float* __restrict__ lib, float* __restrict__ ln) {
    const int row  = blockIdx.x * 4 + (threadIdx.x >> 6);
    const int lane = threadIdx.x & 63;
    const float4 v = reinterpret_cast<const float4*>(lib + (size_t)row * DDIM)[lane];
    float s = v.x * v.x + v.y * v.y + v.z * v.z + v.w * v.w;
#pragma unroll
    for (int off = 32; off > 0; off >>= 1) s += __shfl_down(s, off);
    if (lane == 0) ln[row] = s;
}

// fp16 split with x256 scaling
__device__ __forceinline__ void cvt_split(const f32x4 a, const f32x4 b,
                                          half8& h, half8& l) {
    float v[8] = {a[0], a[1], a[2], a[3], b[0], b[1], b[2], b[3]};
#pragma unroll
    for (int j = 0; j < 8; ++j) {
        const float s = v[j] * 256.0f;
        const _Float16 hh = (_Float16)s;
        const _Float16 ll = (_Float16)(s - (float)hh);
        h[j] = hh; l[j] = ll;
    }
}

// ---------------- pre-split fp32 -> fp16 hi/lo, 32x32-fragment-linear -------
// One launch for BOTH libs: blocks [0, NTOT/128) split reached_lib (+ norms),
// blocks [NTOT/128, NTOT/128+16) split the Q (target) tile images.
__global__ void lp_split32_all(const float* __restrict__ reached,
                               const float* __restrict__ Qp,
                               _Float16* __restrict__ Lsp, _Float16* __restrict__ Qsp,
                               float* __restrict__ ln) {
    const int b    = blockIdx.x;
    const int t    = threadIdx.x;
    const int rg   = t >> 6;
    const int l    = t & 63;
    const int row  = rg * 32 + (l & 31);
    const int k8   = l >> 5;

    const float* srcT;
    _Float16*    dstT;
    float*       lnT;
    int          lnBase = 0;
    if (b < NTOT / 128) {
        srcT = reached + (size_t)b * 128 * DDIM;
        dstT = Lsp + (size_t)b * TILE_HALVES;
        lnT  = ln; lnBase = b * 128;
    } else {
        const int qt = b - NTOT / 128;
        srcT = Qp + (size_t)qt * 128 * DDIM;
        dstT = Qsp + (size_t)qt * TILE_HALVES;
        lnT  = nullptr;
    }
    const float* srcR = srcT + (size_t)row * DDIM;

    float nsum = 0.f;
#pragma unroll
    for (int kb = 0; kb < 8; ++kb) {
#pragma unroll
        for (int kk = 0; kk < 2; ++kk) {
            const float* p = srcR + kb * 32 + kk * 16 + k8 * 8;
            const f32x4 a = *reinterpret_cast<const f32x4*>(p);
            const f32x4 bb = *reinterpret_cast<const f32x4*>(p + 4);
            half8 h, lo; cvt_split(a, bb, h, lo);
            const size_t off = ((size_t)(((kb * 2 + 0) * 4 + rg) * 2 + kk) * 64 + l) * 8;
            *reinterpret_cast<half8*>(dstT + off)        = h;   // hl=0
            *reinterpret_cast<half8*>(dstT + off + 4096) = lo;  // hl=1
            nsum += a[0]*a[0] + a[1]*a[1] + a[2]*a[2] + a[3]*a[3]
                  + bb[0]*bb[0] + bb[1]*bb[1] + bb[2]*bb[2] + bb[3]*bb[3];
        }
    }
    nsum += __shfl_xor(nsum, 32);
    if (lnT != nullptr && k8 == 0) lnT[(size_t)lnBase + row] = nsum;
}

// 12 MFMA for one kb on fragment set RC
#define MFMA12(kb_, RC)                                                          \
    _Pragma("unroll")                                                            \
    for (int kk = 0; kk < 2; ++kk)                                               \
      _Pragma("unroll")                                                          \
      for (int term = 0; term < 3; ++term) {                                     \
        const int ta = (term == 2) ? 1 : 0;                                      \
        const int tb = (term == 1) ? 1 : 0;                                      \
        acc[0] = __builtin_amdgcn_mfma_f32_32x32x16_f16(                         \
            qf[kb_][ta][kk], RC[0][tb][kk], acc[0], 0, 0, 0);                    \
        acc[1] = __builtin_amdgcn_mfma_f32_32x32x16_f16(                         \
            qf[kb_][ta][kk], RC[1][tb][kk], acc[1], 0, 0, 0);                    \
      }

// ---------------- MFMA NN: Q-in-regs, B streamed global->regs, NO LDS -------
// No barriers, no shared memory: the pre-split image is fragment-exact and
// lane-linear, so each wave loads B fragments directly into VGPRs (L1-dedup'd
// across the block's 4 waves). Compiler software-pipelines loads vs MFMA.
__global__ __launch_bounds__(256, 2)
void lp_nn_reg(const _Float16* __restrict__ Qs, const _Float16* __restrict__ Ls,
               const float* __restrict__ ln, int unitsPC, int nchunks,
               float* __restrict__ pscore, int* __restrict__ pidx)
{
    const int nwg  = 16 * nchunks;
    const int hid  = blockIdx.x;
    const int work = (hid & 7) * (nwg >> 3) + (hid >> 3);  // XCD-contiguous (nwg%8==0)
    const int bx   = work & 15;     // query tile (128 rows)
    const int by   = work >> 4;     // lib chunk (unitsPC units of 64 cols)

    const int t    = threadIdx.x;
    const int lane = t & 63;
    const int wid  = t >> 6;        // 0..3: this wave's 32 q-rows within the tile
    const int col  = lane & 31, hi = lane >> 5;

    const _Float16* Qt = Qs + (size_t)bx * TILE_HALVES;
    const int u0 = by * unitsPC;

    // ---- Q fragments -> registers (32 x b128, lane-linear coalesced) ----
    half8 qf[8][2][2];   // [kb][hl][kk]
#pragma unroll
    for (int kb = 0; kb < 8; ++kb)
#pragma unroll
        for (int hl = 0; hl < 2; ++hl)
#pragma unroll
            for (int kk = 0; kk < 2; ++kk)
                qf[kb][hl][kk] = *reinterpret_cast<const half8*>(
                    Qt + ((((kb * 2 + hl) * 4 + wid) * 2) + kk) * 512 + lane * 8);

    float bkey[16];
    int   bidxr[16];
    f32x16 acc[2];
#pragma unroll
    for (int r = 0; r < 16; ++r) { bkey[r] = INF_F; bidxr[r] = 0x7fffffff; }
    acc[0] = (f32x16)(0.f); acc[1] = (f32x16)(0.f);

    for (int un = 0; un < unitsPC; ++un) {
        const int u = u0 + un;
        // fragment base for this unit: tile image + 64-col half select
        const _Float16* Bu = Ls + (size_t)(u >> 1) * TILE_HALVES + (size_t)(u & 1) * 2048;
        const float lnv0 = ln[u * 64 + col];
        const float lnv1 = ln[u * 64 + 32 + col];

#pragma unroll
        for (int kb = 0; kb < 8; ++kb) {
            half8 bf[2][2][2];   // [nf][hl][kk]
#pragma unroll
            for (int nf = 0; nf < 2; ++nf)
#pragma unroll
                for (int hl = 0; hl < 2; ++hl)
#pragma unroll
                    for (int kk = 0; kk < 2; ++kk)
                        bf[nf][hl][kk] = *reinterpret_cast<const half8*>(
                            Bu + (size_t)(((kb * 2 + hl) * 4 + nf) * 1024 + kk * 512 + lane * 8));
            __builtin_amdgcn_s_setprio(1);
            MFMA12(kb, bf)
            __builtin_amdgcn_s_setprio(0);
        }

        // unit finished (full K): fold argmin for these 64 lib cols
#pragma unroll
        for (int nf = 0; nf < 2; ++nf) {
            const int gidx = u * 64 + nf * 32 + col;
            const float lnvs = (nf ? lnv1 : lnv0) * 65536.0f;
#pragma unroll
            for (int r = 0; r < 16; ++r) {
                const float key = fmaf(-2.f, acc[nf][r], lnvs);
                if (key < bkey[r] || (key == bkey[r] && gidx < bidxr[r])) {
                    bkey[r] = key; bidxr[r] = gidx;
                }
                acc[nf][r] = 0.f;
            }
        }
    }

    // butterfly-reduce across the 32 C-columns (low 5 lane bits)
#pragma unroll
    for (int off = 1; off < 32; off <<= 1)
#pragma unroll
        for (int r = 0; r < 16; ++r) {
            const float ok = __shfl_xor(bkey[r], off);
            const int   oi = __shfl_xor(bidxr[r], off);
            if (ok < bkey[r] || (ok == bkey[r] && oi < bidxr[r])) {
                bkey[r] = ok; bidxr[r] = oi;
            }
        }
    // per-wave private argmin: direct global write
    if (col == 0)
#pragma unroll
        for (int r = 0; r < 16; ++r) {
            const int q = bx * 128 + wid * 32 + (r & 3) + 8 * (r >> 2) + 4 * hi;
            pscore[(size_t)q * nchunks + by] = bkey[r];
            pidx  [(size_t)q * nchunks + by] = bidxr[r];
        }
}

// ---------------- fallback MFMA kernel (round-3, in-loop split) -------------
__global__ __launch_bounds__(256, 2)
void lp_nn_mfma_fb(const float* __restrict__ Q, const float* __restrict__ L,
                   const float* __restrict__ ln, int chunkRows,
                   float* __restrict__ pscore, int* __restrict__ pidx, int nchunks)
{
    __shared__ _Float16 Ah[128 * 32];
    __shared__ _Float16 Al[128 * 32];
    __shared__ _Float16 Bh[128 * 32];
    __shared__ _Float16 Bl[128 * 32];
    __shared__ float xk[2][128];
    __shared__ int   xi[2][128];

    const int t    = threadIdx.x;
    const int wid  = t >> 6, lane = t & 63;
    const int wq   = wid >> 1, wl = wid & 1;
    const int col  = lane & 15, rg = lane >> 4;
    const int qbase = blockIdx.x * 128;
    const int chunkBase = blockIdx.y * chunkRows;
    const int srow   = t >> 2;
    const int schunk = t & 3;

    float bkey[4][4];
    int   bidxr[4][4];
#pragma unroll
    for (int mf = 0; mf < 4; ++mf)
#pragma unroll
        for (int i = 0; i < 4; ++i) { bkey[mf][i] = INF_F; bidxr[mf][i] = 0x7fffffff; }

    for (int lt = 0; lt < chunkRows; lt += 128) {
        f32x4 acc[4][4];
#pragma unroll
        for (int mf = 0; mf < 4; ++mf)
#pragma unroll
            for (int nf = 0; nf < 4; ++nf) acc[mf][nf] = (f32x4)(0.f);

        for (int kb = 0; kb < DDIM; kb += 32) {
            __syncthreads();
#pragma unroll
            for (int sr = 0; sr < 2; ++sr) {
                const int r = srow + 64 * sr;
                const int s = schunk ^ SWZ(r);
                {
                    const float* src = Q + (size_t)(qbase + r) * DDIM + kb + schunk * 8;
                    const f32x4 a = *reinterpret_cast<const f32x4*>(src);
                    const f32x4 b = *reinterpret_cast<const f32x4*>(src + 4);
                    half8 h, l; cvt_split(a, b, h, l);
                    *reinterpret_cast<half8*>(&Ah[r * 32 + s * 8]) = h;
                    *reinterpret_cast<half8*>(&Al[r * 32 + s * 8]) = l;
                }
                {
                    const float* src = L + (size_t)(chunkBase + lt + r) * DDIM + kb + schunk * 8;
                    const f32x4 a = *reinterpret_cast<const f32x4*>(src);
                    const f32x4 b = *reinterpret_cast<const f32x4*>(src + 4);
                    half8 h, l; cvt_split(a, b, h, l);
                    *reinterpret_cast<half8*>(&Bh[r * 32 + s * 8]) = h;
                    *reinterpret_cast<half8*>(&Bl[r * 32 + s * 8]) = l;
                }
            }
            __syncthreads();

            half8 ah[4], al[4];
#pragma unroll
            for (int mf = 0; mf < 4; ++mf) {
                const int r = wq * 64 + mf * 16 + col;
                const int s = rg ^ SWZ(r);
                ah[mf] = *reinterpret_cast<const half8*>(&Ah[r * 32 + s * 8]);
                al[mf] = *reinterpret_cast<const half8*>(&Al[r * 32 + s * 8]);
            }
#pragma unroll
            for (int nf = 0; nf < 4; ++nf) {
                const int r = wl * 64 + nf * 16 + col;
                const int s = rg ^ SWZ(r);
                const half8 bh = *reinterpret_cast<const half8*>(&Bh[r * 32 + s * 8]);
                const half8 bl = *reinterpret_cast<const half8*>(&Bl[r * 32 + s * 8]);
#pragma unroll
                for (int mf = 0; mf < 4; ++mf) {
                    acc[mf][nf] = __builtin_amdgcn_mfma_f32_16x16x32_f16(ah[mf], bh, acc[mf][nf], 0, 0, 0);
                    acc[mf][nf] = __builtin_amdgcn_mfma_f32_16x16x32_f16(ah[mf], bl, acc[mf][nf], 0, 0, 0);
                    acc[mf][nf] = __builtin_amdgcn_mfma_f32_16x16x32_f16(al[mf], bh, acc[mf][nf], 0, 0, 0);
                }
            }
        }

#pragma unroll
        for (int nf = 0; nf < 4; ++nf) {
            const int gidx = chunkBase + lt + wl * 64 + nf * 16 + col;
            const float lnv = ln[gidx] * 65536.0f;
#pragma unroll
            for (int mf = 0; mf < 4; ++mf)
#pragma unroll
                for (int i = 0; i < 4; ++i) {
                    const float key = fmaf(-2.f, acc[mf][nf][i], lnv);
                    if (key < bkey[mf][i] || (key == bkey[mf][i] && gidx < bidxr[mf][i])) {
                        bkey[mf][i] = key; bidxr[mf][i] = gidx;
                    }
                }
        }
    }

#pragma unroll
    for (int off = 1; off < 16; off <<= 1)
#pragma unroll
        for (int mf = 0; mf < 4; ++mf)
#pragma unroll
            for (int i = 0; i < 4; ++i) {
                const float ok = __shfl_xor(bkey[mf][i], off);
                const int   oi = __shfl_xor(bidxr[mf][i], off);
                if (ok < bkey[mf][i] || (ok == bkey[mf][i] && oi < bidxr[mf][i])) {
                    bkey[mf][i] = ok; bidxr[mf][i] = oi;
                }
            }
    if (col == 0)
#pragma unroll
        for (int mf = 0; mf < 4; ++mf)
#pragma unroll
            for (int i = 0; i < 4; ++i) {
                const int ql = wq * 64 + mf * 16 + rg * 4 + i;
                xk[wl][ql] = bkey[mf][i];
                xi[wl][ql] = bidxr[mf][i];
            }
    __syncthreads();
    if (t < 128) {
        float bk = xk[0][t]; int bi = xi[0][t];
        const float k2 = xk[1][t]; const int i2 = xi[1][t];
        if (k2 < bk || (k2 == bk && i2 < bi)) { bk = k2; bi = i2; }
        const int q = qbase + t;
        pscore[(size_t)q * nchunks + blockIdx.y] = bk;
        pidx  [(size_t)q * nchunks + blockIdx.y] = bi;
    }
}

// ---------------- finalize: reduce partials, exact distances, value+grad ----
__global__ void lp_finalize(const float* __restrict__ Q,
                            const float* __restrict__ prevL,
                            const float* __restrict__ reachL,
                            const float* __restrict__ ps_p, const int* __restrict__ pi_p,
                            const float* __restrict__ ps_r, const int* __restrict__ pi_r,
                            int ncp, int ncr,
                            float* __restrict__ out)
{
    const int q = blockIdx.x;
    const int lane = threadIdx.x;

    float k1 = (lane < ncp) ? ps_p[(size_t)q * ncp + lane] : INF_F;
    int   i1 = (lane < ncp) ? pi_p[(size_t)q * ncp + lane] : 0x7fffffff;
#pragma unroll
    for (int off = 32; off > 0; off >>= 1) {
        const float ok = __shfl_xor(k1, off);
        const int   oi = __shfl_xor(i1, off);
        if (ok < k1 || (ok == k1 && oi < i1)) { k1 = ok; i1 = oi; }
    }
    float k2 = (lane < ncr) ? ps_r[(size_t)q * ncr + lane] : INF_F;
    int   i2 = (lane < ncr) ? pi_r[(size_t)q * ncr + lane] : 0x7fffffff;
#pragma unroll
    for (int off = 32; off > 0; off >>= 1) {
        const float ok = __shfl_xor(k2, off);
        const int   oi = __shfl_xor(i2, off);
        if (ok < k2 || (ok == k2 && oi < i2)) { k2 = ok; i2 = oi; }
    }

    const float4 tv = reinterpret_cast<const float4*>(Q      + (size_t)q  * DDIM)[lane];
    const float4 e1 = reinterpret_cast<const float4*>(prevL  + (size_t)i1 * DDIM)[lane];
    const float4 e2 = reinterpret_cast<const float4*>(reachL + (size_t)i2 * DDIM)[lane];
    const float4 d1 = {tv.x - e1.x, tv.y - e1.y, tv.z - e1.z, tv.w - e1.w};
    const float4 d2 = {tv.x - e2.x, tv.y - e2.y, tv.z - e2.z, tv.w - e2.w};
    float s1 = d1.x * d1.x + d1.y * d1.y + d1.z * d1.z + d1.w * d1.w;
    float s2 = d2.x * d2.x + d2.y * d2.y + d2.z * d2.z + d2.w * d2.w;
#pragma unroll
    for (int off = 32; off > 0; off >>= 1) {
        s1 += __shfl_xor(s1, off);
        s2 += __shfl_xor(s2, off);
    }
    const float r1 = sqrtf(s1), r2 = sqrtf(s2);
    float4 g;
    g.x = d1.x / r1 - d2.x / r2;
    g.y = d1.y / r1 - d2.y / r2;
    g.z = d1.z / r1 - d2.z / r2;
    g.w = d1.w / r1 - d2.w / r2;
    reinterpret_cast<float4*>(out + BATCH + (size_t)q * DDIM)[lane] = g;
    if (lane == 0) out[q] = r1 - r2;
}

extern "C" void kernel_launch(void* const* d_in, const int* in_sizes, int n_in,
                              void* d_out, int out_size, void* d_ws, size_t ws_size,
                              hipStream_t stream) {
    const float* target_lib  = (const float*)d_in[0];
    const float* reached_lib = (const float*)d_in[1];
    const float* Qp     = target_lib  + (size_t)NPREV * DDIM;  // targets
    const float* prevL  = reached_lib;                          // prev
    const float* reachL = reached_lib + (size_t)NPREV * DDIM;  // reached

    float* ws     = (float*)d_ws;
    float* ln_all = ws;                                   // 65536 f
    float* ps_p   = ln_all + NTOT;                        // 2048*PWP f
    float* ps_r   = ps_p + (size_t)BATCH * PWP;           // 2048*PWR f
    int*   pi_p   = (int*)(ps_r + (size_t)BATCH * PWR);
    int*   pi_r   = pi_p + (size_t)BATCH * PWP;
    _Float16* Qsp = (_Float16*)(pi_r + (size_t)BATCH * PWR);           // 2 MB
    _Float16* Lsp = Qsp + (size_t)(BATCH / 128) * TILE_HALVES;         // 64 MB
    float* out    = (float*)d_out;

    const size_t need = (size_t)(NTOT + 2 * BATCH * (PWP + PWR)) * 4
                      + (size_t)(BATCH / 128 + NTOT / 128) * TILE_HALVES * 2;

    if (ws_size >= need) {
        lp_split32_all<<<NTOT / 128 + BATCH / 128, 256, 0, stream>>>(
            reached_lib, Qp, Lsp, Qsp, ln_all);
        lp_nn_reg<<<16 * PWP, 256, 0, stream>>>(
            Qsp, Lsp, ln_all, UPC_P, PWP, ps_p, pi_p);
        lp_nn_reg<<<16 * PWR, 256, 0, stream>>>(
            Qsp, Lsp + (size_t)(NPREV / 128) * TILE_HALVES,
            ln_all + NPREV, UPC_R, PWR, ps_r, pi_r);
        lp_finalize<<<BATCH, 64, 0, stream>>>(
            Qp, prevL, reachL, ps_p, pi_p, ps_r, pi_r, PWP, PWR, out);
    } else {
        lp_norms<<<NTOT / 4, 256, 0, stream>>>(reached_lib, ln_all);
        lp_nn_mfma_fb<<<dim3(BATCH / 128, BNC_P), 256, 0, stream>>>(
            Qp, prevL, ln_all, 2048, ps_p, pi_p, BNC_P);
        lp_nn_mfma_fb<<<dim3(BATCH / 128, BNC_R), 256, 0, stream>>>(
            Qp, reachL, ln_all + NPREV, 128, ps_r, pi_r, BNC_R);
        lp_finalize<<<BATCH, 64, 0, stream>>>(
            Qp, prevL, reachL, ps_p, pi_p, ps_r, pi_r, BNC_P, BNC_R, out);
    }
}

// Round 18
// 233.598 us; speedup vs baseline: 1.1310x; 1.1310x over previous
//
#include <hip/hip_runtime.h>
#include <math.h>

#define NTOT   65536
#define DDIM   256
#define BATCH  2048
#define NPREV  (NTOT - BATCH)   // 63488

#define PWP    32               // partial width, prev (32 chunks)
#define PWR    32               // partial width, reached
#define UPC_P  31               // units (64-col x 256-k) per chunk, prev
#define UPC_R  1                // reached
#define BNC_P  31               // fallback chunking
#define BNC_R  16

#define INF_F 3.402823466e+38f
#define SWZ(r) ((((r) & 3)) ^ ((((r) >> 2) & 3)))

typedef float  f32x4  __attribute__((ext_vector_type(4)));
typedef float  f32x16 __attribute__((ext_vector_type(16)));
typedef _Float16 half8 __attribute__((ext_vector_type(8)));

#define TILE_HALVES 65536   // per 128-row tile image (128r x 256k x hi/lo)

#define SCHED_FENCE() __builtin_amdgcn_sched_barrier(0)
#define RAW_BARRIER() do { SCHED_FENCE(); __builtin_amdgcn_s_barrier(); SCHED_FENCE(); } while (0)
#define VMCNT2()  do { asm volatile("s_waitcnt vmcnt(2)" ::: "memory"); SCHED_FENCE(); } while (0)
#define VMCNT0()  do { asm volatile("s_waitcnt vmcnt(0)" ::: "memory"); SCHED_FENCE(); } while (0)
#define LGKM0()   do { asm volatile("s_waitcnt lgkmcnt(0)" ::: "memory"); SCHED_FENCE(); } while (0)

// ---------------- row norms (fallback path) ----------------
__global__ void lp_norms(const float* __restrict__ lib, float* __restrict__ ln) {
    const int row  = blockIdx.x * 4 + (threadIdx.x >> 6);
    const int lane = threadIdx.x & 63;
    const float4 v = reinterpret_cast<const float4*>(lib + (size_t)row * DDIM)[lane];
    float s = v.x * v.x + v.y * v.y + v.z * v.z + v.w * v.w;
#pragma unroll
    for (int off = 32; off > 0; off >>= 1) s += __shfl_down(s, off);
    if (lane == 0) ln[row] = s;
}

// fp16 split with x256 scaling
__device__ __forceinline__ void cvt_split(const f32x4 a, const f32x4 b,
                                          half8& h, half8& l) {
    float v[8] = {a[0], a[1], a[2], a[3], b[0], b[1], b[2], b[3]};
#pragma unroll
    for (int j = 0; j < 8; ++j) {
        const float s = v[j] * 256.0f;
        const _Float16 hh = (_Float16)s;
        const _Float16 ll = (_Float16)(s - (float)hh);
        h[j] = hh; l[j] = ll;
    }
}

// ---------------- pre-split fp32 -> fp16 hi/lo, 32x32-fragment-linear -------
// One launch for BOTH libs: blocks [0, NTOT/128) split reached_lib (+ norms),
// blocks [NTOT/128, NTOT/128+16) split the Q (target) tile images.
__global__ void lp_split32_all(const float* __restrict__ reached,
                               const float* __restrict__ Qp,
                               _Float16* __restrict__ Lsp, _Float16* __restrict__ Qsp,
                               float* __restrict__ ln) {
    const int b    = blockIdx.x;
    const int t    = threadIdx.x;
    const int rg   = t >> 6;
    const int l    = t & 63;
    const int row  = rg * 32 + (l & 31);
    const int k8   = l >> 5;

    const float* srcT;
    _Float16*    dstT;
    float*       lnT;
    int          lnBase = 0;
    if (b < NTOT / 128) {
        srcT = reached + (size_t)b * 128 * DDIM;
        dstT = Lsp + (size_t)b * TILE_HALVES;
        lnT  = ln; lnBase = b * 128;
    } else {
        const int qt = b - NTOT / 128;
        srcT = Qp + (size_t)qt * 128 * DDIM;
        dstT = Qsp + (size_t)qt * TILE_HALVES;
        lnT  = nullptr;
    }
    const float* srcR = srcT + (size_t)row * DDIM;

    float nsum = 0.f;
#pragma unroll
    for (int kb = 0; kb < 8; ++kb) {
#pragma unroll
        for (int kk = 0; kk < 2; ++kk) {
            const float* p = srcR + kb * 32 + kk * 16 + k8 * 8;
            const f32x4 a = *reinterpret_cast<const f32x4*>(p);
            const f32x4 bb = *reinterpret_cast<const f32x4*>(p + 4);
            half8 h, lo; cvt_split(a, bb, h, lo);
            const size_t off = ((size_t)(((kb * 2 + 0) * 4 + rg) * 2 + kk) * 64 + l) * 8;
            *reinterpret_cast<half8*>(dstT + off)        = h;   // hl=0
            *reinterpret_cast<half8*>(dstT + off + 4096) = lo;  // hl=1
            nsum += a[0]*a[0] + a[1]*a[1] + a[2]*a[2] + a[3]*a[3]
                  + bb[0]*bb[0] + bb[1]*bb[1] + bb[2]*bb[2] + bb[3]*bb[3];
        }
    }
    nsum += __shfl_xor(nsum, 32);
    if (lnT != nullptr && k8 == 0) lnT[(size_t)lnBase + row] = nsum;
}

__device__ __forceinline__ void gload16(const _Float16* g, _Float16* lds) {
    __builtin_amdgcn_global_load_lds(
        (const __attribute__((address_space(1))) void*)g,
        (__attribute__((address_space(3))) void*)lds, 16, 0, 0);
}

// ---------------- MFMA NN: Q-in-regs, 3-buffer 1-barrier pipeline (r14) -----
// Per step: stage(s+2) issue; vmcnt(2) [stage(s+1) done]; ONE barrier;
// lgkmcnt(0) [free]; 12 MFMA on PRE-READ regs; post-read bf(s+1) -> other set.
#define NN_STEP(kb_, RC, RN, STAGE_OK, VM, READ_OK)                              \
  {                                                                              \
    const int s_ = un * 8 + (kb_);                                               \
    if (STAGE_OK) stageL((s_ + 2) % 3, s_ + 2);                                  \
    VM;                                                                          \
    RAW_BARRIER();                                                               \
    LGKM0();                                                                     \
    __builtin_amdgcn_s_setprio(1);                                               \
    _Pragma("unroll")                                                            \
    for (int kk = 0; kk < 2; ++kk)                                               \
      _Pragma("unroll")                                                          \
      for (int term = 0; term < 3; ++term) {                                     \
        const int ta = (term == 2) ? 1 : 0;                                      \
        const int tb = (term == 1) ? 1 : 0;                                      \
        acc[0] = __builtin_amdgcn_mfma_f32_32x32x16_f16(                         \
            qf[kb_][ta][kk], RC[0][tb][kk], acc[0], 0, 0, 0);                    \
        acc[1] = __builtin_amdgcn_mfma_f32_32x32x16_f16(                         \
            qf[kb_][ta][kk], RC[1][tb][kk], acc[1], 0, 0, 0);                    \
      }                                                                          \
    __builtin_amdgcn_s_setprio(0);                                               \
    if (READ_OK) {                                                               \
      const _Float16* Bn = &LB[(s_ + 1) % 3][0];                                 \
      _Pragma("unroll")                                                          \
      for (int nf = 0; nf < 2; ++nf)                                             \
        _Pragma("unroll")                                                        \
        for (int hl = 0; hl < 2; ++hl)                                           \
          _Pragma("unroll")                                                      \
          for (int kk = 0; kk < 2; ++kk)                                         \
            RN[nf][hl][kk] = *reinterpret_cast<const half8*>(                    \
                Bn + hl * 2048 + nf * 1024 + kk * 512 + lane * 8);               \
    }                                                                            \
  }

__global__ __launch_bounds__(256, 2)
void lp_nn_mfma10(const _Float16* __restrict__ Qs, const _Float16* __restrict__ Ls,
                  const float* __restrict__ ln, int unitsPC, int nchunks,
                  float* __restrict__ pscore, int* __restrict__ pidx)
{
    __shared__ _Float16 LB[3][4096];   // 3 x 8 KB: L unit-kb triple buffer
    __shared__ float lnLds[2048];      // chunk row norms (<= unitsPC*64 used)

    const int nwg  = 16 * nchunks;
    const int hid  = blockIdx.x;
    const int work = (hid & 7) * (nwg >> 3) + (hid >> 3);  // XCD-contiguous (nwg%8==0)
    const int bx   = work & 15;     // query tile (128 rows)
    const int by   = work >> 4;     // lib chunk (unitsPC units of 64 cols)

    const int t    = threadIdx.x;
    const int lane = t & 63;
    const int wid  = t >> 6;        // 0..3: this wave's 32 q-rows within the tile
    const int col  = lane & 31, hi = lane >> 5;

    const _Float16* Qt = Qs + (size_t)bx * TILE_HALVES;
    const int u0    = by * unitsPC;
    const int NSTEP = unitsPC * 8;

    // ---- Q fragments -> registers (32 x b128, lane-linear coalesced) ----
    half8 qf[8][2][2];   // [kb][hl][kk]
#pragma unroll
    for (int kb = 0; kb < 8; ++kb)
#pragma unroll
        for (int hl = 0; hl < 2; ++hl)
#pragma unroll
            for (int kk = 0; kk < 2; ++kk)
                qf[kb][hl][kk] = *reinterpret_cast<const half8*>(
                    Qt + ((((kb * 2 + hl) * 4 + wid) * 2) + kk) * 512 + lane * 8);

    auto stageL = [&](int buf, int s) {   // 8 KB: one unit's kb block (2 vm ops/wave)
        const int u = u0 + (s >> 3), kb = s & 7;
        const int tile = u >> 1, half = u & 1;
        const _Float16* base = Ls + (size_t)tile * TILE_HALVES;
#pragma unroll
        for (int hl = 0; hl < 2; ++hl)
            gload16(base + ((kb * 2 + hl) * 4 + half * 2) * 1024 + t * 8,
                    &LB[buf][hl * 2048 + wid * 512]);
    };

    float bkey[16];
    int   bidxr[16];
    f32x16 acc[2];
#pragma unroll
    for (int r = 0; r < 16; ++r) { bkey[r] = INF_F; bidxr[r] = 0x7fffffff; }
    acc[0] = (f32x16)(0.f); acc[1] = (f32x16)(0.f);

    auto fold = [&](int un) {
        const int u = u0 + un;
        const float lnv0 = lnLds[un * 64 + col];
        const float lnv1 = lnLds[un * 64 + 32 + col];
#pragma unroll
        for (int nf = 0; nf < 2; ++nf) {
            const int gidx = u * 64 + nf * 32 + col;
            const float lnvs = (nf ? lnv1 : lnv0) * 65536.0f;
#pragma unroll
            for (int r = 0; r < 16; ++r) {
                const float key = fmaf(-2.f, acc[nf][r], lnvs);
                if (key < bkey[r] || (key == bkey[r] && gidx < bidxr[r])) {
                    bkey[r] = key; bidxr[r] = gidx;
                }
                acc[nf][r] = 0.f;
            }
        }
    };

    // ---- prologue: ln chunk (8 KB), stage(0), stage(1); pre-read bf(0) ----
    {
        const float* lsrc = ln + (size_t)u0 * 64;
#pragma unroll
        for (int j = 0; j < 2; ++j)
            __builtin_amdgcn_global_load_lds(
                (const __attribute__((address_space(1))) void*)(lsrc + j * 1024 + t * 4),
                (__attribute__((address_space(3))) void*)(&lnLds[j * 1024 + wid * 256]),
                16, 0, 0);
    }
    stageL(0, 0);
    stageL(1, 1);
    VMCNT2();          // ln + stage(0) complete; stage(1) still in flight
    RAW_BARRIER();

    half8 bfA[2][2][2], bfB[2][2][2];
#pragma unroll
    for (int nf = 0; nf < 2; ++nf)
#pragma unroll
        for (int hl = 0; hl < 2; ++hl)
#pragma unroll
            for (int kk = 0; kk < 2; ++kk)
                bfA[nf][hl][kk] = *reinterpret_cast<const half8*>(
                    &LB[0][0] + hl * 2048 + nf * 1024 + kk * 512 + lane * 8);

    // ---- hot units (fully static: always stage, always VMCNT2) ----
    for (int un = 0; un < unitsPC - 1; ++un) {
        NN_STEP(0, bfA, bfB, true, VMCNT2(), true)
        NN_STEP(1, bfB, bfA, true, VMCNT2(), true)
        NN_STEP(2, bfA, bfB, true, VMCNT2(), true)
        NN_STEP(3, bfB, bfA, true, VMCNT2(), true)
        NN_STEP(4, bfA, bfB, true, VMCNT2(), true)
        NN_STEP(5, bfB, bfA, true, VMCNT2(), true)
        NN_STEP(6, bfA, bfB, true, VMCNT2(), true)
        NN_STEP(7, bfB, bfA, true, VMCNT2(), true)
        fold(un);
    }
    // ---- peeled last unit ----
    {
        const int un = unitsPC - 1;
        NN_STEP(0, bfA, bfB, true,  VMCNT2(), true)
        NN_STEP(1, bfB, bfA, true,  VMCNT2(), true)
        NN_STEP(2, bfA, bfB, true,  VMCNT2(), true)
        NN_STEP(3, bfB, bfA, true,  VMCNT2(), true)
        NN_STEP(4, bfA, bfB, true,  VMCNT2(), true)
        NN_STEP(5, bfB, bfA, true,  VMCNT2(), true)
        NN_STEP(6, bfA, bfB, false, VMCNT0(), true)
        NN_STEP(7, bfB, bfA, false, VMCNT0(), false)
        fold(un);
    }

    // butterfly-reduce across the 32 C-columns (low 5 lane bits)
#pragma unroll
    for (int off = 1; off < 32; off <<= 1)
#pragma unroll
        for (int r = 0; r < 16; ++r) {
            const float ok = __shfl_xor(bkey[r], off);
            const int   oi = __shfl_xor(bidxr[r], off);
            if (ok < bkey[r] || (ok == bkey[r] && oi < bidxr[r])) {
                bkey[r] = ok; bidxr[r] = oi;
            }
        }
    // per-wave private argmin: direct global write
    if (col == 0)
#pragma unroll
        for (int r = 0; r < 16; ++r) {
            const int q = bx * 128 + wid * 32 + (r & 3) + 8 * (r >> 2) + 4 * hi;
            pscore[(size_t)q * nchunks + by] = bkey[r];
            pidx  [(size_t)q * nchunks + by] = bidxr[r];
        }
}

// ---------------- fallback MFMA kernel (round-3, in-loop split) -------------
__global__ __launch_bounds__(256, 2)
void lp_nn_mfma_fb(const float* __restrict__ Q, const float* __restrict__ L,
                   const float* __restrict__ ln, int chunkRows,
                   float* __restrict__ pscore, int* __restrict__ pidx, int nchunks)
{
    __shared__ _Float16 Ah[128 * 32];
    __shared__ _Float16 Al[128 * 32];
    __shared__ _Float16 Bh[128 * 32];
    __shared__ _Float16 Bl[128 * 32];
    __shared__ float xk[2][128];
    __shared__ int   xi[2][128];

    const int t    = threadIdx.x;
    const int wid  = t >> 6, lane = t & 63;
    const int wq   = wid >> 1, wl = wid & 1;
    const int col  = lane & 15, rg = lane >> 4;
    const int qbase = blockIdx.x * 128;
    const int chunkBase = blockIdx.y * chunkRows;
    const int srow   = t >> 2;
    const int schunk = t & 3;

    float bkey[4][4];
    int   bidxr[4][4];
#pragma unroll
    for (int mf = 0; mf < 4; ++mf)
#pragma unroll
        for (int i = 0; i < 4; ++i) { bkey[mf][i] = INF_F; bidxr[mf][i] = 0x7fffffff; }

    for (int lt = 0; lt < chunkRows; lt += 128) {
        f32x4 acc[4][4];
#pragma unroll
        for (int mf = 0; mf < 4; ++mf)
#pragma unroll
            for (int nf = 0; nf < 4; ++nf) acc[mf][nf] = (f32x4)(0.f);

        for (int kb = 0; kb < DDIM; kb += 32) {
            __syncthreads();
#pragma unroll
            for (int sr = 0; sr < 2; ++sr) {
                const int r = srow + 64 * sr;
                const int s = schunk ^ SWZ(r);
                {
                    const float* src = Q + (size_t)(qbase + r) * DDIM + kb + schunk * 8;
                    const f32x4 a = *reinterpret_cast<const f32x4*>(src);
                    const f32x4 b = *reinterpret_cast<const f32x4*>(src + 4);
                    half8 h, l; cvt_split(a, b, h, l);
                    *reinterpret_cast<half8*>(&Ah[r * 32 + s * 8]) = h;
                    *reinterpret_cast<half8*>(&Al[r * 32 + s * 8]) = l;
                }
                {
                    const float* src = L + (size_t)(chunkBase + lt + r) * DDIM + kb + schunk * 8;
                    const f32x4 a = *reinterpret_cast<const f32x4*>(src);
                    const f32x4 b = *reinterpret_cast<const f32x4*>(src + 4);
                    half8 h, l; cvt_split(a, b, h, l);
                    *reinterpret_cast<half8*>(&Bh[r * 32 + s * 8]) = h;
                    *reinterpret_cast<half8*>(&Bl[r * 32 + s * 8]) = l;
                }
            }
            __syncthreads();

            half8 ah[4], al[4];
#pragma unroll
            for (int mf = 0; mf < 4; ++mf) {
                const int r = wq * 64 + mf * 16 + col;
                const int s = rg ^ SWZ(r);
                ah[mf] = *reinterpret_cast<const half8*>(&Ah[r * 32 + s * 8]);
                al[mf] = *reinterpret_cast<const half8*>(&Al[r * 32 + s * 8]);
            }
#pragma unroll
            for (int nf = 0; nf < 4; ++nf) {
                const int r = wl * 64 + nf * 16 + col;
                const int s = rg ^ SWZ(r);
                const half8 bh = *reinterpret_cast<const half8*>(&Bh[r * 32 + s * 8]);
                const half8 bl = *reinterpret_cast<const half8*>(&Bl[r * 32 + s * 8]);
#pragma unroll
                for (int mf = 0; mf < 4; ++mf) {
                    acc[mf][nf] = __builtin_amdgcn_mfma_f32_16x16x32_f16(ah[mf], bh, acc[mf][nf], 0, 0, 0);
                    acc[mf][nf] = __builtin_amdgcn_mfma_f32_16x16x32_f16(ah[mf], bl, acc[mf][nf], 0, 0, 0);
                    acc[mf][nf] = __builtin_amdgcn_mfma_f32_16x16x32_f16(al[mf], bh, acc[mf][nf], 0, 0, 0);
                }
            }
        }

#pragma unroll
        for (int nf = 0; nf < 4; ++nf) {
            const int gidx = chunkBase + lt + wl * 64 + nf * 16 + col;
            const float lnv = ln[gidx] * 65536.0f;
#pragma unroll
            for (int mf = 0; mf < 4; ++mf)
#pragma unroll
                for (int i = 0; i < 4; ++i) {
                    const float key = fmaf(-2.f, acc[mf][nf][i], lnv);
                    if (key < bkey[mf][i] || (key == bkey[mf][i] && gidx < bidxr[mf][i])) {
                        bkey[mf][i] = key; bidxr[mf][i] = gidx;
                    }
                }
        }
    }

#pragma unroll
    for (int off = 1; off < 16; off <<= 1)
#pragma unroll
        for (int mf = 0; mf < 4; ++mf)
#pragma unroll
            for (int i = 0; i < 4; ++i) {
                const float ok = __shfl_xor(bkey[mf][i], off);
                const int   oi = __shfl_xor(bidxr[mf][i], off);
                if (ok < bkey[mf][i] || (ok == bkey[mf][i] && oi < bidxr[mf][i])) {
                    bkey[mf][i] = ok; bidxr[mf][i] = oi;
                }
            }
    if (col == 0)
#pragma unroll
        for (int mf = 0; mf < 4; ++mf)
#pragma unroll
            for (int i = 0; i < 4; ++i) {
                const int ql = wq * 64 + mf * 16 + rg * 4 + i;
                xk[wl][ql] = bkey[mf][i];
                xi[wl][ql] = bidxr[mf][i];
            }
    __syncthreads();
    if (t < 128) {
        float bk = xk[0][t]; int bi = xi[0][t];
        const float k2 = xk[1][t]; const int i2 = xi[1][t];
        if (k2 < bk || (k2 == bk && i2 < bi)) { bk = k2; bi = i2; }
        const int q = qbase + t;
        pscore[(size_t)q * nchunks + blockIdx.y] = bk;
        pidx  [(size_t)q * nchunks + blockIdx.y] = bi;
    }
}

// ---------------- finalize: reduce partials, exact distances, value+grad ----
__global__ void lp_finalize(const float* __restrict__ Q,
                            const float* __restrict__ prevL,
                            const float* __restrict__ reachL,
                            const float* __restrict__ ps_p, const int* __restrict__ pi_p,
                            const float* __restrict__ ps_r, const int* __restrict__ pi_r,
                            int ncp, int ncr,
                            float* __restrict__ out)
{
    const int q = blockIdx.x;
    const int lane = threadIdx.x;

    float k1 = (lane < ncp) ? ps_p[(size_t)q * ncp + lane] : INF_F;
    int   i1 = (lane < ncp) ? pi_p[(size_t)q * ncp + lane] : 0x7fffffff;
#pragma unroll
    for (int off = 32; off > 0; off >>= 1) {
        const float ok = __shfl_xor(k1, off);
        const int   oi = __shfl_xor(i1, off);
        if (ok < k1 || (ok == k1 && oi < i1)) { k1 = ok; i1 = oi; }
    }
    float k2 = (lane < ncr) ? ps_r[(size_t)q * ncr + lane] : INF_F;
    int   i2 = (lane < ncr) ? pi_r[(size_t)q * ncr + lane] : 0x7fffffff;
#pragma unroll
    for (int off = 32; off > 0; off >>= 1) {
        const float ok = __shfl_xor(k2, off);
        const int   oi = __shfl_xor(i2, off);
        if (ok < k2 || (ok == k2 && oi < i2)) { k2 = ok; i2 = oi; }
    }

    const float4 tv = reinterpret_cast<const float4*>(Q      + (size_t)q  * DDIM)[lane];
    const float4 e1 = reinterpret_cast<const float4*>(prevL  + (size_t)i1 * DDIM)[lane];
    const float4 e2 = reinterpret_cast<const float4*>(reachL + (size_t)i2 * DDIM)[lane];
    const float4 d1 = {tv.x - e1.x, tv.y - e1.y, tv.z - e1.z, tv.w - e1.w};
    const float4 d2 = {tv.x - e2.x, tv.y - e2.y, tv.z - e2.z, tv.w - e2.w};
    float s1 = d1.x * d1.x + d1.y * d1.y + d1.z * d1.z + d1.w * d1.w;
    float s2 = d2.x * d2.x + d2.y * d2.y + d2.z * d2.z + d2.w * d2.w;
#pragma unroll
    for (int off = 32; off > 0; off >>= 1) {
        s1 += __shfl_xor(s1, off);
        s2 += __shfl_xor(s2, off);
    }
    const float r1 = sqrtf(s1), r2 = sqrtf(s2);
    float4 g;
    g.x = d1.x / r1 - d2.x / r2;
    g.y = d1.y / r1 - d2.y / r2;
    g.z = d1.z / r1 - d2.z / r2;
    g.w = d1.w / r1 - d2.w / r2;
    reinterpret_cast<float4*>(out + BATCH + (size_t)q * DDIM)[lane] = g;
    if (lane == 0) out[q] = r1 - r2;
}

extern "C" void kernel_launch(void* const* d_in, const int* in_sizes, int n_in,
                              void* d_out, int out_size, void* d_ws, size_t ws_size,
                              hipStream_t stream) {
    const float* target_lib  = (const float*)d_in[0];
    const float* reached_lib = (const float*)d_in[1];
    const float* Qp     = target_lib  + (size_t)NPREV * DDIM;  // targets
    const float* prevL  = reached_lib;                          // prev
    const float* reachL = reached_lib + (size_t)NPREV * DDIM;  // reached

    float* ws     = (float*)d_ws;
    float* ln_all = ws;                                   // 65536 f
    float* ps_p   = ln_all + NTOT;                        // 2048*PWP f
    float* ps_r   = ps_p + (size_t)BATCH * PWP;           // 2048*PWR f
    int*   pi_p   = (int*)(ps_r + (size_t)BATCH * PWR);
    int*   pi_r   = pi_p + (size_t)BATCH * PWP;
    _Float16* Qsp = (_Float16*)(pi_r + (size_t)BATCH * PWR);           // 2 MB
    _Float16* Lsp = Qsp + (size_t)(BATCH / 128) * TILE_HALVES;         // 64 MB
    float* out    = (float*)d_out;

    const size_t need = (size_t)(NTOT + 2 * BATCH * (PWP + PWR)) * 4
                      + (size_t)(BATCH / 128 + NTOT / 128) * TILE_HALVES * 2;

    if (ws_size >= need) {
        lp_split32_all<<<NTOT / 128 + BATCH / 128, 256, 0, stream>>>(
            reached_lib, Qp, Lsp, Qsp, ln_all);
        lp_nn_mfma10<<<16 * PWP, 256, 0, stream>>>(
            Qsp, Lsp, ln_all, UPC_P, PWP, ps_p, pi_p);
        lp_nn_mfma10<<<16 * PWR, 256, 0, stream>>>(
            Qsp, Lsp + (size_t)(NPREV / 128) * TILE_HALVES,
            ln_all + NPREV, UPC_R, PWR, ps_r, pi_r);
        lp_finalize<<<BATCH, 64, 0, stream>>>(
            Qp, prevL, reachL, ps_p, pi_p, ps_r, pi_r, PWP, PWR, out);
    } else {
        lp_norms<<<NTOT / 4, 256, 0, stream>>>(reached_lib, ln_all);
        lp_nn_mfma_fb<<<dim3(BATCH / 128, BNC_P), 256, 0, stream>>>(
            Qp, prevL, ln_all, 2048, ps_p, pi_p, BNC_P);
        lp_nn_mfma_fb<<<dim3(BATCH / 128, BNC_R), 256, 0, stream>>>(
            Qp, reachL, ln_all + NPREV, 128, ps_r, pi_r, BNC_R);
        lp_finalize<<<BATCH, 64, 0, stream>>>(
            Qp, prevL, reachL, ps_p, pi_p, ps_r, pi_r, BNC_P, BNC_R, out);
    }
}